// Round 1
// baseline (3439.734 us; speedup 1.0000x reference)
//
#include <hip/hip_runtime.h>

// LSTM: B=512, T=128, D=512, H=512, gates [i|j|f|o], FORGET_BIAS=1.0
// Persistent kernel: 256 blocks (16 row-tiles x 16 gate-col-tiles), 1 block/CU.
// fp16 MFMA (16x16x32), c-state in registers, h ping-pong f16 in ws,
// software device-wide barrier per step (monotone counter).

#define Bsz 512
#define Tt  128
#define Dd  512
#define Hh  512

typedef _Float16 half8 __attribute__((ext_vector_type(8)));
typedef _Float16 half4 __attribute__((ext_vector_type(4)));
typedef float    f32x4 __attribute__((ext_vector_type(4)));

__device__ __forceinline__ float sigm(float v) {
    return 1.0f / (1.0f + __expf(-v));
}
__device__ __forceinline__ float tanhfast(float v) {
    float e = __expf(-2.0f * fabsf(v));
    float r = (1.0f - e) / (1.0f + e);
    return (v < 0.0f) ? -r : r;
}

// Pack W [1024, 2048] f32 -> fragment-major f16.
// idx = ((((c*4+g)*2+nf)*32+kc)*64+lane); element j of the 8-group is
// W[kc*32 + (lane>>4)*8 + j][g*512 + c*32 + nf*16 + (lane&15)].
// Same k-slot mapping is used for the A fragments -> MFMA-consistent.
__global__ __launch_bounds__(256) void pack_w_kernel(const float* __restrict__ W,
                                                     _Float16* __restrict__ Wp) {
    int idx = blockIdx.x * 256 + threadIdx.x;   // 0 .. 262143
    int l  = idx & 63;
    int kc = (idx >> 6) & 31;
    int nf = (idx >> 11) & 1;
    int g  = (idx >> 12) & 3;
    int c  = idx >> 14;                          // 0..15
    int n  = g * Hh + c * 32 + nf * 16 + (l & 15);
    int k0 = kc * 32 + (l >> 4) * 8;
    half8 v;
#pragma unroll
    for (int j = 0; j < 8; ++j)
        v[j] = (_Float16)W[(size_t)(k0 + j) * (4 * Hh) + n];
    *reinterpret_cast<half8*>(Wp + (size_t)idx * 8) = v;
}

__global__ __launch_bounds__(256) void lstm_kernel(
    const float* __restrict__ x, const _Float16* __restrict__ Wp,
    const float* __restrict__ bias, _Float16* __restrict__ hbuf0,
    _Float16* __restrict__ hbuf1, unsigned int* __restrict__ barrier_cnt,
    float* __restrict__ out) {

    __shared__ _Float16 Atile[32 * 1024];   // 64 KB, XOR-swizzled rows
    __shared__ float    Z[4][32][33];       // gate exchange, padded stride

    const int tid  = threadIdx.x;
    const int lane = tid & 63;
    const int wv   = tid >> 6;              // wave id == gate id (i,j,f,o)
    const int l15  = lane & 15;
    const int l16  = lane >> 4;

    // blockIdx mapping: row-tile = bid>>4 so the 16 col-tiles of a row-group
    // spread over XCDs and each XCD's L2 keeps only 2 W column-slices resident.
    const int rt = blockIdx.x >> 4;         // row tile   0..15
    const int ct = blockIdx.x & 15;         // col tile   0..15

    const float bias0 = bias[wv * Hh + ct * 32 + l15];
    const float bias1 = bias[wv * Hh + ct * 32 + 16 + l15];

    const int srow = tid >> 3;              // staging row 0..31
    const int sl8  = tid & 7;

    const int erow = tid >> 3;              // epilogue row 0..31
    const int ecol = (tid & 7) * 4;         // epilogue col0

    float creg[4] = {0.f, 0.f, 0.f, 0.f};   // cell state, register-resident

    const _Float16* wpg = Wp + (size_t)(ct * 4 + wv) * (2 * 32 * 64 * 8);

#pragma unroll 1
    for (int t = 0; t < Tt; ++t) {
        const _Float16* hin = (t & 1) ? hbuf1 : hbuf0;
        _Float16* hout      = (t & 1) ? hbuf0 : hbuf1;

        // ---------- stage A = [x_t | h] as f16 into swizzled LDS ----------
        {
            const float*    xp = x + ((size_t)(rt * 32 + srow) * Tt + t) * Dd;
            const _Float16* hp = hin + (size_t)(rt * 32 + srow) * Hh;
#pragma unroll
            for (int i = 0; i < 16; ++i) {
                int k8 = sl8 + i * 8;       // 16B-group index 0..127
                int k  = k8 * 8;
                half8 v;
                if (k < Dd) {
                    const float4* p = reinterpret_cast<const float4*>(xp + k);
                    float4 f0 = p[0], f1 = p[1];
                    v[0] = (_Float16)f0.x; v[1] = (_Float16)f0.y;
                    v[2] = (_Float16)f0.z; v[3] = (_Float16)f0.w;
                    v[4] = (_Float16)f1.x; v[5] = (_Float16)f1.y;
                    v[6] = (_Float16)f1.z; v[7] = (_Float16)f1.w;
                } else {
                    v = *reinterpret_cast<const half8*>(hp + (k - Dd));
                }
                int byteoff = srow * 2048 + ((k8 * 16) ^ ((srow & 7) << 4));
                *reinterpret_cast<half8*>(reinterpret_cast<char*>(Atile) + byteoff) = v;
            }
        }
        __syncthreads();

        // ---------- MFMA: z[32 rows x 32 cols of gate wv] ----------
        f32x4 acc00 = {0,0,0,0}, acc01 = {0,0,0,0};
        f32x4 acc10 = {0,0,0,0}, acc11 = {0,0,0,0};
#pragma unroll 4
        for (int kc = 0; kc < 32; ++kc) {
            int row0 = l15;
            int row1 = 16 + l15;
            int kg   = kc * 4 + l16;
            int o0 = row0 * 2048 + ((kg * 16) ^ ((row0 & 7) << 4));
            int o1 = row1 * 2048 + ((kg * 16) ^ ((row1 & 7) << 4));
            half8 a0 = *reinterpret_cast<const half8*>(reinterpret_cast<const char*>(Atile) + o0);
            half8 a1 = *reinterpret_cast<const half8*>(reinterpret_cast<const char*>(Atile) + o1);
            half8 b0 = *reinterpret_cast<const half8*>(wpg + ((size_t)(kc)      * 64 + lane) * 8);
            half8 b1 = *reinterpret_cast<const half8*>(wpg + ((size_t)(32 + kc) * 64 + lane) * 8);
            acc00 = __builtin_amdgcn_mfma_f32_16x16x32_f16(a0, b0, acc00, 0, 0, 0);
            acc10 = __builtin_amdgcn_mfma_f32_16x16x32_f16(a1, b0, acc10, 0, 0, 0);
            acc01 = __builtin_amdgcn_mfma_f32_16x16x32_f16(a0, b1, acc01, 0, 0, 0);
            acc11 = __builtin_amdgcn_mfma_f32_16x16x32_f16(a1, b1, acc11, 0, 0, 0);
        }

        // ---------- scatter z (+bias) to LDS for cross-wave gate exchange ----------
#pragma unroll
        for (int reg = 0; reg < 4; ++reg) {
            int zr = l16 * 4 + reg;     // C/D layout: col=lane&15, row=(lane>>4)*4+reg
            Z[wv][zr][l15]           = acc00[reg] + bias0;
            Z[wv][16 + zr][l15]      = acc10[reg] + bias0;
            Z[wv][zr][16 + l15]      = acc01[reg] + bias1;
            Z[wv][16 + zr][16 + l15] = acc11[reg] + bias1;
        }
        __syncthreads();

        // ---------- pointwise: c,h update (c in registers) ----------
        float hv[4];
#pragma unroll
        for (int q = 0; q < 4; ++q) {
            int colq = ecol + q;
            float zi = Z[0][erow][colq];
            float zj = Z[1][erow][colq];
            float zf = Z[2][erow][colq];
            float zo = Z[3][erow][colq];
            float cn = creg[q] * sigm(zf + 1.0f) + sigm(zi) * tanhfast(zj);
            creg[q] = cn;
            hv[q] = tanhfast(cn) * sigm(zo);
        }
        {
            size_t off = (size_t)(rt * 32 + erow) * Hh + ct * 32 + ecol;
            half4 hh;
            hh[0] = (_Float16)hv[0]; hh[1] = (_Float16)hv[1];
            hh[2] = (_Float16)hv[2]; hh[3] = (_Float16)hv[3];
            *reinterpret_cast<half4*>(hout + off) = hh;
            if (t == Tt - 1) {
                f32x4 fo;
                fo[0] = hv[0]; fo[1] = hv[1]; fo[2] = hv[2]; fo[3] = hv[3];
                *reinterpret_cast<f32x4*>(out + off) = fo;
            }
        }

        // ---------- device-wide barrier (skip after last step) ----------
        if (t < Tt - 1) {
            __syncthreads();                 // all h stores of this block issued
            if (tid == 0) {
                __threadfence();             // release: h visible device-wide
                atomicAdd(barrier_cnt, 1u);  // device-scope RMW at coherent point
                unsigned int target = 256u * (unsigned)(t + 1);
                while (__hip_atomic_load(barrier_cnt, __ATOMIC_RELAXED,
                                         __HIP_MEMORY_SCOPE_AGENT) < target) {
                    __builtin_amdgcn_s_sleep(2);
                }
                __threadfence();             // acquire: invalidate L1/stale L2
            }
            __syncthreads();
        }
    }
}

extern "C" void kernel_launch(void* const* d_in, const int* in_sizes, int n_in,
                              void* d_out, int out_size, void* d_ws, size_t ws_size,
                              hipStream_t stream) {
    const float* x  = (const float*)d_in[0];   // [512,128,512] f32
    const float* W  = (const float*)d_in[1];   // [1024,2048] f32
    const float* bb = (const float*)d_in[2];   // [2048] f32
    float* out = (float*)d_out;                // [512,512] f32

    char* ws = (char*)d_ws;
    _Float16* Wp = (_Float16*)ws;                                  // 4 MB
    _Float16* h0 = (_Float16*)(ws + 4u * 1024 * 1024);             // 512 KB
    _Float16* h1 = (_Float16*)(ws + 4u * 1024 * 1024 + 512 * 1024);// 512 KB
    unsigned int* cnt = (unsigned int*)(ws + 5u * 1024 * 1024);

    hipMemsetAsync(h0, 0, (size_t)Bsz * Hh * sizeof(_Float16), stream);
    hipMemsetAsync(cnt, 0, 64, stream);
    pack_w_kernel<<<1024, 256, 0, stream>>>(W, Wp);
    lstm_kernel<<<256, 256, 0, stream>>>(x, Wp, bb, h0, h1, cnt, out);
}

// Round 2
// 3378.074 us; speedup vs baseline: 1.0183x; 1.0183x over previous
//
#include <hip/hip_runtime.h>

// LSTM: B=512, T=128, D=512, H=512, gates [i|j|f|o], FORGET_BIAS=1.0
// Single persistent kernel, 256 blocks x 256 threads, 1 block/CU.
// Per 16-step chunk: (a) barrier-free GEMM phase zx = b + x@Wx (f16, private),
// (b) recurrence with Wh fragments in LDS, h via global ping-pong + device barrier.

#define Bsz 512
#define Tt  128
#define Dd  512
#define Hh  512
#define NB  256

typedef _Float16 half8 __attribute__((ext_vector_type(8)));
typedef _Float16 half4 __attribute__((ext_vector_type(4)));
typedef float    f32x4 __attribute__((ext_vector_type(4)));

__device__ __forceinline__ float sigm(float v) { return 1.0f / (1.0f + __expf(-v)); }
__device__ __forceinline__ float tanhfast(float v) {
    float e = __expf(-2.0f * fabsf(v));
    float r = (1.0f - e) / (1.0f + e);
    return (v < 0.0f) ? -r : r;
}

// Pack W -> fragment-major f16 for both Wx (rows 0..511) and Wh (rows 512..1023).
// Slice layout per (f = ct*4+wv): [hn(2)][kc(16)][lane(64)][8], element j =
// W[koff + kc*32 + (lane>>4)*8 + j][wv*512 + ct*32 + hn*16 + (lane&15)].
__global__ __launch_bounds__(256) void pack_kernel(const float* __restrict__ W,
                                                   _Float16* __restrict__ Wxp,
                                                   _Float16* __restrict__ Whp) {
    __shared__ _Float16 Tl[512 * 32];   // [k][n] tile, 32 KB
    const int bid = blockIdx.x, tid = threadIdx.x;
    const int which = bid >> 6;          // 0: Wx, 1: Wh
    const int f = bid & 63, ct = f >> 2, wv = f & 3;
    const int koff = which * 512;
    const int ncol0 = wv * Hh + ct * 32;

#pragma unroll
    for (int p = 0; p < 16; ++p) {
        int row = p * 32 + (tid >> 3);
        int c4  = (tid & 7) * 4;
        float4 v = *reinterpret_cast<const float4*>(W + (size_t)(koff + row) * 2048 + ncol0 + c4);
        Tl[row * 32 + c4 + 0] = (_Float16)v.x;
        Tl[row * 32 + c4 + 1] = (_Float16)v.y;
        Tl[row * 32 + c4 + 2] = (_Float16)v.z;
        Tl[row * 32 + c4 + 3] = (_Float16)v.w;
    }
    __syncthreads();

    _Float16* dst = (which ? Whp : Wxp) + (size_t)f * 16384;
#pragma unroll
    for (int i = 0; i < 8; ++i) {
        int gi  = tid * 8 + i;               // 0..2047
        int hn  = gi >> 10;
        int kc  = (gi >> 6) & 15;
        int ln  = gi & 63;
        int l15 = ln & 15, l16 = ln >> 4;
        half8 v;
#pragma unroll
        for (int j = 0; j < 8; ++j)
            v[j] = Tl[(kc * 32 + l16 * 8 + j) * 32 + hn * 16 + l15];
        *reinterpret_cast<half8*>(dst + (size_t)gi * 8) = v;
    }
}

__global__ __launch_bounds__(256) void lstm_all(
    const float* __restrict__ x, const _Float16* __restrict__ Wxp,
    const _Float16* __restrict__ Whp, const float* __restrict__ bias,
    _Float16* __restrict__ zxbuf, _Float16* __restrict__ h0,
    _Float16* __restrict__ h1, unsigned int* __restrict__ cnt,
    float* __restrict__ out, int Tc) {

    __shared__ half8 Wlds[4 * 2 * 16 * 64];          // 131072 B: [wv][hn][kc][lane]
    __shared__ __align__(16) char arena[16896];       // GEMM x-staging (16384) U Z[4][32][33] f32

    const int tid = threadIdx.x, lane = tid & 63, wv = tid >> 6;
    const int l15 = lane & 15, l16 = lane >> 4;
    const int bid = blockIdx.x;
    // same-rt blocks land on one XCD (round-robin dispatch heuristic)
    const int rt = (bid & 7) * 2 + ((bid >> 3) & 1);  // 0..15
    const int ct = bid >> 4;                          // 0..15

    const float bias0 = bias[wv * Hh + ct * 32 + l15]      + (wv == 2 ? 1.0f : 0.0f);
    const float bias1 = bias[wv * Hh + ct * 32 + 16 + l15] + (wv == 2 ? 1.0f : 0.0f);

    const int srow = tid >> 3, sl8 = tid & 7;         // GEMM staging
    const int erow = tid >> 3, ecol = (tid & 7) * 4;  // pointwise
    float creg[4] = {0.f, 0.f, 0.f, 0.f};

    const int nChunks = Tt / Tc;

    for (int cc = 0; cc < nChunks; ++cc) {
        // ================= GEMM phase: zx = bias + x@Wx (barrier-free) =================
        {   // load Wx fragments -> LDS
            const half8* s8 = reinterpret_cast<const half8*>(Wxp + (size_t)(ct * 4) * 16384);
#pragma unroll
            for (int i = 0; i < 32; ++i) Wlds[tid + i * 256] = s8[tid + i * 256];
        }
        __syncthreads();

        for (int t16 = 0; t16 < Tc; ++t16) {
            const int tg = cc * Tc + t16;
            f32x4 acc00 = {bias0, bias0, bias0, bias0};
            f32x4 acc10 = acc00;
            f32x4 acc01 = {bias1, bias1, bias1, bias1};
            f32x4 acc11 = acc01;

#pragma unroll
            for (int kh = 0; kh < 2; ++kh) {
                // stage 32 rows x 256 cols of x as f16 (swizzled)
                const float* xr = x + ((size_t)(rt * 32 + srow) * Tt + tg) * Dd + kh * 256;
#pragma unroll
                for (int i = 0; i < 4; ++i) {
                    int k8 = sl8 + i * 8;            // 0..31 (16B groups)
                    float4 p0 = *reinterpret_cast<const float4*>(xr + k8 * 8);
                    float4 p1 = *reinterpret_cast<const float4*>(xr + k8 * 8 + 4);
                    half8 v;
                    v[0] = (_Float16)p0.x; v[1] = (_Float16)p0.y;
                    v[2] = (_Float16)p0.z; v[3] = (_Float16)p0.w;
                    v[4] = (_Float16)p1.x; v[5] = (_Float16)p1.y;
                    v[6] = (_Float16)p1.z; v[7] = (_Float16)p1.w;
                    *reinterpret_cast<half8*>(arena + srow * 512 + ((k8 * 16) ^ ((srow & 7) << 4))) = v;
                }
                __syncthreads();
#pragma unroll
                for (int k2 = 0; k2 < 8; ++k2) {
                    int kc = kh * 8 + k2;
                    int kg = k2 * 4 + l16;
                    half8 a0 = *reinterpret_cast<const half8*>(
                        arena + l15 * 512 + ((kg * 16) ^ ((l15 & 7) << 4)));
                    half8 a1 = *reinterpret_cast<const half8*>(
                        arena + (16 + l15) * 512 + ((kg * 16) ^ ((l15 & 7) << 4)));
                    half8 b0 = Wlds[((wv * 2 + 0) * 16 + kc) * 64 + lane];
                    half8 b1 = Wlds[((wv * 2 + 1) * 16 + kc) * 64 + lane];
                    acc00 = __builtin_amdgcn_mfma_f32_16x16x32_f16(a0, b0, acc00, 0, 0, 0);
                    acc10 = __builtin_amdgcn_mfma_f32_16x16x32_f16(a1, b0, acc10, 0, 0, 0);
                    acc01 = __builtin_amdgcn_mfma_f32_16x16x32_f16(a0, b1, acc01, 0, 0, 0);
                    acc11 = __builtin_amdgcn_mfma_f32_16x16x32_f16(a1, b1, acc11, 0, 0, 0);
                }
                __syncthreads();
            }
            // store zx fragments (block-private, f16): order [00,10,01,11]
            _Float16* zp = zxbuf + (((size_t)bid * Tc + t16) * 4 + wv) * 1024 + lane * 16;
            half8 z0, z1;
#pragma unroll
            for (int r = 0; r < 4; ++r) {
                z0[r] = (_Float16)acc00[r]; z0[4 + r] = (_Float16)acc10[r];
                z1[r] = (_Float16)acc01[r]; z1[4 + r] = (_Float16)acc11[r];
            }
            *reinterpret_cast<half8*>(zp)     = z0;
            *reinterpret_cast<half8*>(zp + 8) = z1;
        }

        {   // load Wh fragments -> LDS
            const half8* s8 = reinterpret_cast<const half8*>(Whp + (size_t)(ct * 4) * 16384);
#pragma unroll
            for (int i = 0; i < 32; ++i) Wlds[tid + i * 256] = s8[tid + i * 256];
        }
        __syncthreads();

        // ================= recurrence phase =================
        for (int t16 = 0; t16 < Tc; ++t16) {
            const int tg = cc * Tc + t16;
            const _Float16* hin = (tg & 1) ? h1 : h0;
            _Float16* hout      = (tg & 1) ? h0 : h1;

            // acc init from zx (includes bias)
            const _Float16* zp = zxbuf + (((size_t)bid * Tc + t16) * 4 + wv) * 1024 + lane * 16;
            half8 z0 = *reinterpret_cast<const half8*>(zp);
            half8 z1 = *reinterpret_cast<const half8*>(zp + 8);
            f32x4 acc00, acc10, acc01, acc11;
#pragma unroll
            for (int r = 0; r < 4; ++r) {
                acc00[r] = (float)z0[r]; acc10[r] = (float)z0[4 + r];
                acc01[r] = (float)z1[r]; acc11[r] = (float)z1[4 + r];
            }

            const _Float16* hrow0 = hin + (size_t)(rt * 32 + l15) * Hh + l16 * 8;
            const _Float16* hrow1 = hrow0 + 16 * Hh;
#pragma unroll
            for (int kc = 0; kc < 16; ++kc) {
                half8 a0 = *reinterpret_cast<const half8*>(hrow0 + kc * 32);
                half8 a1 = *reinterpret_cast<const half8*>(hrow1 + kc * 32);
                half8 b0 = Wlds[((wv * 2 + 0) * 16 + kc) * 64 + lane];
                half8 b1 = Wlds[((wv * 2 + 1) * 16 + kc) * 64 + lane];
                acc00 = __builtin_amdgcn_mfma_f32_16x16x32_f16(a0, b0, acc00, 0, 0, 0);
                acc10 = __builtin_amdgcn_mfma_f32_16x16x32_f16(a1, b0, acc10, 0, 0, 0);
                acc01 = __builtin_amdgcn_mfma_f32_16x16x32_f16(a0, b1, acc01, 0, 0, 0);
                acc11 = __builtin_amdgcn_mfma_f32_16x16x32_f16(a1, b1, acc11, 0, 0, 0);
            }

            // scatter z to LDS for cross-wave gate exchange
            float* Zf = (float*)arena;
#pragma unroll
            for (int reg = 0; reg < 4; ++reg) {
                int zr = l16 * 4 + reg;           // C/D: col=lane&15, row=(lane>>4)*4+reg
                Zf[(wv * 32 + zr) * 33 + l15]            = acc00[reg];
                Zf[(wv * 32 + 16 + zr) * 33 + l15]       = acc10[reg];
                Zf[(wv * 32 + zr) * 33 + 16 + l15]       = acc01[reg];
                Zf[(wv * 32 + 16 + zr) * 33 + 16 + l15]  = acc11[reg];
            }
            __syncthreads();

            // pointwise c/h update (c register-resident)
            float hv[4];
#pragma unroll
            for (int q = 0; q < 4; ++q) {
                int colq = ecol + q;
                float zi = Zf[(0 * 32 + erow) * 33 + colq];
                float zj = Zf[(1 * 32 + erow) * 33 + colq];
                float zf = Zf[(2 * 32 + erow) * 33 + colq];
                float zo = Zf[(3 * 32 + erow) * 33 + colq];
                float cn = creg[q] * sigm(zf) + sigm(zi) * tanhfast(zj);  // FORGET_BIAS folded
                creg[q] = cn;
                hv[q] = tanhfast(cn) * sigm(zo);
            }
            {
                size_t off = (size_t)(rt * 32 + erow) * Hh + ct * 32 + ecol;
                half4 hh;
                hh[0] = (_Float16)hv[0]; hh[1] = (_Float16)hv[1];
                hh[2] = (_Float16)hv[2]; hh[3] = (_Float16)hv[3];
                *reinterpret_cast<half4*>(hout + off) = hh;
                if (tg == Tt - 1) {
                    f32x4 fo; fo[0] = hv[0]; fo[1] = hv[1]; fo[2] = hv[2]; fo[3] = hv[3];
                    *reinterpret_cast<f32x4*>(out + off) = fo;
                }
            }

            // device-wide barrier (monotone counter), skip after last step
            if (tg < Tt - 1) {
                __syncthreads();
                if (tid == 0) {
                    __threadfence();
                    atomicAdd(cnt, 1u);
                    unsigned int target = 256u * (unsigned)(tg + 1);
                    while (__hip_atomic_load(cnt, __ATOMIC_RELAXED,
                                             __HIP_MEMORY_SCOPE_AGENT) < target) {
                        __builtin_amdgcn_s_sleep(1);
                    }
                    __threadfence();
                }
                __syncthreads();
            }
        }
    }
}

extern "C" void kernel_launch(void* const* d_in, const int* in_sizes, int n_in,
                              void* d_out, int out_size, void* d_ws, size_t ws_size,
                              hipStream_t stream) {
    const float* x  = (const float*)d_in[0];   // [512,128,512] f32
    const float* W  = (const float*)d_in[1];   // [1024,2048] f32
    const float* bb = (const float*)d_in[2];   // [2048] f32
    float* out = (float*)d_out;                // [512,512] f32

    char* ws = (char*)d_ws;
    _Float16* Wxp = (_Float16*)ws;                                   // 2 MB
    _Float16* Whp = (_Float16*)(ws + (2u << 20));                    // 2 MB
    _Float16* h0  = (_Float16*)(ws + (4u << 20));                    // 512 KB
    _Float16* h1  = (_Float16*)(ws + (4u << 20) + (512u << 10));     // 512 KB
    unsigned int* cnt = (unsigned int*)(ws + (5u << 20));
    _Float16* zxbuf = (_Float16*)(ws + (6u << 20));                  // Tc * 2 MB

    int Tc = 16;
    while (Tc > 1 && (size_t)(6u << 20) + (size_t)NB * Tc * 4096 * 2 > ws_size) Tc >>= 1;

    hipMemsetAsync(h0, 0, (size_t)Bsz * Hh * sizeof(_Float16), stream);
    hipMemsetAsync(cnt, 0, 64, stream);
    pack_kernel<<<128, 256, 0, stream>>>(W, Wxp, Whp);
    lstm_all<<<256, 256, 0, stream>>>(x, Wxp, Whp, bb, zxbuf, h0, h1, cnt, out, Tc);
}

// Round 3
// 1853.320 us; speedup vs baseline: 1.8560x; 1.8227x over previous
//
#include <hip/hip_runtime.h>

// LSTM: B=512, T=128, D=512, H=512, gates [i|j|f|o], FORGET_BIAS=1.0
// Single persistent kernel, 256 blocks x 256 threads, 1 block/CU.
// Per 16-step chunk: (a) barrier-free GEMM phase zx = b + x@Wx (f16, private),
// (b) recurrence with Wh fragments in LDS; h exchanged via device-scope (sc1)
// relaxed atomics; fence-free flag/master/go barrier (no buffer_wbl2/inv).

#define Bsz 512
#define Tt  128
#define Dd  512
#define Hh  512
#define NB  256

typedef _Float16 half8 __attribute__((ext_vector_type(8)));
typedef _Float16 half4 __attribute__((ext_vector_type(4)));
typedef float    f32x4 __attribute__((ext_vector_type(4)));
typedef unsigned long long u64;

__device__ __forceinline__ float sigm(float v) { return 1.0f / (1.0f + __expf(-v)); }
__device__ __forceinline__ float tanhfast(float v) {
    float e = __expf(-2.0f * fabsf(v));
    float r = (1.0f - e) / (1.0f + e);
    return (v < 0.0f) ? -r : r;
}
__device__ __forceinline__ half8 mk8(u64 lo, u64 hi) {
    half4 a = __builtin_bit_cast(half4, lo);
    half4 b = __builtin_bit_cast(half4, hi);
    half8 r;
    r[0] = a[0]; r[1] = a[1]; r[2] = a[2]; r[3] = a[3];
    r[4] = b[0]; r[5] = b[1]; r[6] = b[2]; r[7] = b[3];
    return r;
}

// Pack W -> fragment-major f16 for both Wx (rows 0..511) and Wh (rows 512..1023).
// Slice layout per (f = ct*4+wv): [hn(2)][kc(16)][lane(64)][8], element j =
// W[koff + kc*32 + (lane>>4)*8 + j][wv*512 + ct*32 + hn*16 + (lane&15)].
__global__ __launch_bounds__(256) void pack_kernel(const float* __restrict__ W,
                                                   _Float16* __restrict__ Wxp,
                                                   _Float16* __restrict__ Whp) {
    __shared__ _Float16 Tl[512 * 32];   // [k][n] tile, 32 KB
    const int bid = blockIdx.x, tid = threadIdx.x;
    const int which = bid >> 6;          // 0: Wx, 1: Wh
    const int f = bid & 63, ct = f >> 2, wv = f & 3;
    const int koff = which * 512;
    const int ncol0 = wv * Hh + ct * 32;

#pragma unroll
    for (int p = 0; p < 16; ++p) {
        int row = p * 32 + (tid >> 3);
        int c4  = (tid & 7) * 4;
        float4 v = *reinterpret_cast<const float4*>(W + (size_t)(koff + row) * 2048 + ncol0 + c4);
        Tl[row * 32 + c4 + 0] = (_Float16)v.x;
        Tl[row * 32 + c4 + 1] = (_Float16)v.y;
        Tl[row * 32 + c4 + 2] = (_Float16)v.z;
        Tl[row * 32 + c4 + 3] = (_Float16)v.w;
    }
    __syncthreads();

    _Float16* dst = (which ? Whp : Wxp) + (size_t)f * 16384;
#pragma unroll
    for (int i = 0; i < 8; ++i) {
        int gi  = tid * 8 + i;               // 0..2047
        int hn  = gi >> 10;
        int kc  = (gi >> 6) & 15;
        int ln  = gi & 63;
        int l15 = ln & 15, l16 = ln >> 4;
        half8 v;
#pragma unroll
        for (int j = 0; j < 8; ++j)
            v[j] = Tl[(kc * 32 + l16 * 8 + j) * 32 + hn * 16 + l15];
        *reinterpret_cast<half8*>(dst + (size_t)gi * 8) = v;
    }
}

__global__ __launch_bounds__(256) void lstm_all(
    const float* __restrict__ x, const _Float16* __restrict__ Wxp,
    const _Float16* __restrict__ Whp, const float* __restrict__ bias,
    _Float16* __restrict__ zxbuf, _Float16* __restrict__ h0,
    _Float16* __restrict__ h1, unsigned int* __restrict__ flags,
    unsigned int* __restrict__ go, float* __restrict__ out, int Tc) {

    __shared__ half8 Wlds[4 * 2 * 16 * 64];          // 131072 B: [wv][hn][kc][lane]
    __shared__ __align__(16) char arena[16896];       // GEMM x-staging (16384) U Z[4][32][33] f32

    const int tid = threadIdx.x, lane = tid & 63, wv = tid >> 6;
    const int l15 = lane & 15, l16 = lane >> 4;
    const int bid = blockIdx.x;
    const int rt = (bid & 7) * 2 + ((bid >> 3) & 1);  // 0..15
    const int ct = bid >> 4;                          // 0..15

    const float bias0 = bias[wv * Hh + ct * 32 + l15]      + (wv == 2 ? 1.0f : 0.0f);
    const float bias1 = bias[wv * Hh + ct * 32 + 16 + l15] + (wv == 2 ? 1.0f : 0.0f);

    const int srow = tid >> 3, sl8 = tid & 7;         // GEMM staging
    const int erow = tid >> 3, ecol = (tid & 7) * 4;  // pointwise
    float creg[4] = {0.f, 0.f, 0.f, 0.f};

    const int nChunks = Tt / Tc;

    for (int cc = 0; cc < nChunks; ++cc) {
        // ================= GEMM phase: zx = bias + x@Wx (barrier-free) =================
        {   // load Wx fragments -> LDS
            const half8* s8 = reinterpret_cast<const half8*>(Wxp + (size_t)(ct * 4) * 16384);
#pragma unroll
            for (int i = 0; i < 32; ++i) Wlds[tid + i * 256] = s8[tid + i * 256];
        }
        __syncthreads();

        for (int t16 = 0; t16 < Tc; ++t16) {
            const int tg = cc * Tc + t16;
            f32x4 acc00 = {bias0, bias0, bias0, bias0};
            f32x4 acc10 = acc00;
            f32x4 acc01 = {bias1, bias1, bias1, bias1};
            f32x4 acc11 = acc01;

#pragma unroll
            for (int kh = 0; kh < 2; ++kh) {
                // stage 32 rows x 256 cols of x as f16 (swizzled)
                const float* xr = x + ((size_t)(rt * 32 + srow) * Tt + tg) * Dd + kh * 256;
#pragma unroll
                for (int i = 0; i < 4; ++i) {
                    int k8 = sl8 + i * 8;            // 0..31 (16B groups)
                    float4 p0 = *reinterpret_cast<const float4*>(xr + k8 * 8);
                    float4 p1 = *reinterpret_cast<const float4*>(xr + k8 * 8 + 4);
                    half8 v;
                    v[0] = (_Float16)p0.x; v[1] = (_Float16)p0.y;
                    v[2] = (_Float16)p0.z; v[3] = (_Float16)p0.w;
                    v[4] = (_Float16)p1.x; v[5] = (_Float16)p1.y;
                    v[6] = (_Float16)p1.z; v[7] = (_Float16)p1.w;
                    *reinterpret_cast<half8*>(arena + srow * 512 + ((k8 * 16) ^ ((srow & 7) << 4))) = v;
                }
                __syncthreads();
#pragma unroll
                for (int k2 = 0; k2 < 8; ++k2) {
                    int kc = kh * 8 + k2;
                    int kg = k2 * 4 + l16;
                    half8 a0 = *reinterpret_cast<const half8*>(
                        arena + l15 * 512 + ((kg * 16) ^ ((l15 & 7) << 4)));
                    half8 a1 = *reinterpret_cast<const half8*>(
                        arena + (16 + l15) * 512 + ((kg * 16) ^ ((l15 & 7) << 4)));
                    half8 b0 = Wlds[((wv * 2 + 0) * 16 + kc) * 64 + lane];
                    half8 b1 = Wlds[((wv * 2 + 1) * 16 + kc) * 64 + lane];
                    acc00 = __builtin_amdgcn_mfma_f32_16x16x32_f16(a0, b0, acc00, 0, 0, 0);
                    acc10 = __builtin_amdgcn_mfma_f32_16x16x32_f16(a1, b0, acc10, 0, 0, 0);
                    acc01 = __builtin_amdgcn_mfma_f32_16x16x32_f16(a0, b1, acc01, 0, 0, 0);
                    acc11 = __builtin_amdgcn_mfma_f32_16x16x32_f16(a1, b1, acc11, 0, 0, 0);
                }
                __syncthreads();
            }
            // store zx fragments (block-private, f16, normal cached stores)
            _Float16* zp = zxbuf + (((size_t)bid * Tc + t16) * 4 + wv) * 1024 + lane * 16;
            half8 z0, z1;
#pragma unroll
            for (int r = 0; r < 4; ++r) {
                z0[r] = (_Float16)acc00[r]; z0[4 + r] = (_Float16)acc10[r];
                z1[r] = (_Float16)acc01[r]; z1[4 + r] = (_Float16)acc11[r];
            }
            *reinterpret_cast<half8*>(zp)     = z0;
            *reinterpret_cast<half8*>(zp + 8) = z1;
        }

        {   // load Wh fragments -> LDS
            const half8* s8 = reinterpret_cast<const half8*>(Whp + (size_t)(ct * 4) * 16384);
#pragma unroll
            for (int i = 0; i < 32; ++i) Wlds[tid + i * 256] = s8[tid + i * 256];
        }
        __syncthreads();

        // ================= recurrence phase =================
        for (int t16 = 0; t16 < Tc; ++t16) {
            const int tg = cc * Tc + t16;
            const _Float16* hin = (tg & 1) ? h1 : h0;
            _Float16* hout      = (tg & 1) ? h0 : h1;

            // acc init from zx (includes bias)
            const _Float16* zp = zxbuf + (((size_t)bid * Tc + t16) * 4 + wv) * 1024 + lane * 16;
            half8 z0 = *reinterpret_cast<const half8*>(zp);
            half8 z1 = *reinterpret_cast<const half8*>(zp + 8);
            f32x4 acc00, acc10, acc01, acc11;
#pragma unroll
            for (int r = 0; r < 4; ++r) {
                acc00[r] = (float)z0[r]; acc10[r] = (float)z0[4 + r];
                acc01[r] = (float)z1[r]; acc11[r] = (float)z1[4 + r];
            }

            // h A-fragments: device-coherent (sc1) 8B atomic loads, no fences
            const u64* hq0 = reinterpret_cast<const u64*>(hin + (size_t)(rt * 32 + l15) * Hh) + l16 * 2;
            const u64* hq1 = hq0 + 16 * (Hh / 4);
#pragma unroll
            for (int kc = 0; kc < 16; ++kc) {
                u64 a0l = __hip_atomic_load(hq0 + kc * 8,     __ATOMIC_RELAXED, __HIP_MEMORY_SCOPE_AGENT);
                u64 a0h = __hip_atomic_load(hq0 + kc * 8 + 1, __ATOMIC_RELAXED, __HIP_MEMORY_SCOPE_AGENT);
                u64 a1l = __hip_atomic_load(hq1 + kc * 8,     __ATOMIC_RELAXED, __HIP_MEMORY_SCOPE_AGENT);
                u64 a1h = __hip_atomic_load(hq1 + kc * 8 + 1, __ATOMIC_RELAXED, __HIP_MEMORY_SCOPE_AGENT);
                half8 a0 = mk8(a0l, a0h);
                half8 a1 = mk8(a1l, a1h);
                half8 b0 = Wlds[((wv * 2 + 0) * 16 + kc) * 64 + lane];
                half8 b1 = Wlds[((wv * 2 + 1) * 16 + kc) * 64 + lane];
                acc00 = __builtin_amdgcn_mfma_f32_16x16x32_f16(a0, b0, acc00, 0, 0, 0);
                acc10 = __builtin_amdgcn_mfma_f32_16x16x32_f16(a1, b0, acc10, 0, 0, 0);
                acc01 = __builtin_amdgcn_mfma_f32_16x16x32_f16(a0, b1, acc01, 0, 0, 0);
                acc11 = __builtin_amdgcn_mfma_f32_16x16x32_f16(a1, b1, acc11, 0, 0, 0);
            }

            // scatter z to LDS for cross-wave gate exchange
            float* Zf = (float*)arena;
#pragma unroll
            for (int reg = 0; reg < 4; ++reg) {
                int zr = l16 * 4 + reg;           // C/D: col=lane&15, row=(lane>>4)*4+reg
                Zf[(wv * 32 + zr) * 33 + l15]            = acc00[reg];
                Zf[(wv * 32 + 16 + zr) * 33 + l15]       = acc10[reg];
                Zf[(wv * 32 + zr) * 33 + 16 + l15]       = acc01[reg];
                Zf[(wv * 32 + 16 + zr) * 33 + 16 + l15]  = acc11[reg];
            }
            __syncthreads();

            // pointwise c/h update (c register-resident)
            float hv[4];
#pragma unroll
            for (int q = 0; q < 4; ++q) {
                int colq = ecol + q;
                float zi = Zf[(0 * 32 + erow) * 33 + colq];
                float zj = Zf[(1 * 32 + erow) * 33 + colq];
                float zf = Zf[(2 * 32 + erow) * 33 + colq];
                float zo = Zf[(3 * 32 + erow) * 33 + colq];
                float cn = creg[q] * sigm(zf) + sigm(zi) * tanhfast(zj);  // FORGET_BIAS folded
                creg[q] = cn;
                hv[q] = tanhfast(cn) * sigm(zo);
            }
            {
                size_t off = (size_t)(rt * 32 + erow) * Hh + ct * 32 + ecol;
                half4 hh;
                hh[0] = (_Float16)hv[0]; hh[1] = (_Float16)hv[1];
                hh[2] = (_Float16)hv[2]; hh[3] = (_Float16)hv[3];
                u64 hraw = __builtin_bit_cast(u64, hh);
                __hip_atomic_store(reinterpret_cast<u64*>(hout) + (off >> 2), hraw,
                                   __ATOMIC_RELAXED, __HIP_MEMORY_SCOPE_AGENT);
                if (tg == Tt - 1) {
                    f32x4 fo; fo[0] = hv[0]; fo[1] = hv[1]; fo[2] = hv[2]; fo[3] = hv[3];
                    *reinterpret_cast<f32x4*>(out + off) = fo;
                }
            }

            // ---- fence-free device barrier: flags + master + go ----
            if (tg < Tt - 1) {
                const unsigned e = (unsigned)tg + 1u;
                __syncthreads();   // emits s_waitcnt vmcnt(0): all sc1 h-stores complete
                if (bid == 0) {
                    if (tid > 0) {
                        while (__hip_atomic_load(&flags[tid * 16], __ATOMIC_RELAXED,
                                                 __HIP_MEMORY_SCOPE_AGENT) < e)
                            __builtin_amdgcn_s_sleep(2);
                    }
                    __syncthreads();
                    if (tid == 0)
                        __hip_atomic_store(go, e, __ATOMIC_RELAXED, __HIP_MEMORY_SCOPE_AGENT);
                } else {
                    if (tid == 0) {
                        __hip_atomic_store(&flags[bid * 16], e, __ATOMIC_RELAXED,
                                           __HIP_MEMORY_SCOPE_AGENT);
                        while (__hip_atomic_load(go, __ATOMIC_RELAXED,
                                                 __HIP_MEMORY_SCOPE_AGENT) < e)
                            __builtin_amdgcn_s_sleep(2);
                    }
                    __syncthreads();
                }
            }
        }
    }
}

extern "C" void kernel_launch(void* const* d_in, const int* in_sizes, int n_in,
                              void* d_out, int out_size, void* d_ws, size_t ws_size,
                              hipStream_t stream) {
    const float* x  = (const float*)d_in[0];   // [512,128,512] f32
    const float* W  = (const float*)d_in[1];   // [1024,2048] f32
    const float* bb = (const float*)d_in[2];   // [2048] f32
    float* out = (float*)d_out;                // [512,512] f32

    char* ws = (char*)d_ws;
    _Float16* Wxp = (_Float16*)ws;                                   // 2 MB
    _Float16* Whp = (_Float16*)(ws + (2u << 20));                    // 2 MB
    _Float16* h0  = (_Float16*)(ws + (4u << 20));                    // 512 KB
    _Float16* h1  = (_Float16*)(ws + (4u << 20) + (512u << 10));     // 512 KB
    unsigned int* flags = (unsigned int*)(ws + (5u << 20));          // 256 x 64B
    unsigned int* go    = (unsigned int*)(ws + (5u << 20) + 16384);  // 1 dword
    _Float16* zxbuf = (_Float16*)(ws + (6u << 20));                  // Tc * 2 MB

    int Tc = 16;
    while (Tc > 1 && (size_t)(6u << 20) + (size_t)NB * Tc * 4096 * 2 > ws_size) Tc >>= 1;

    hipMemsetAsync(h0, 0, (size_t)Bsz * Hh * sizeof(_Float16), stream);
    hipMemsetAsync((void*)flags, 0, 32768, stream);   // flags + go
    pack_kernel<<<128, 256, 0, stream>>>(W, Wxp, Whp);
    lstm_all<<<256, 256, 0, stream>>>(x, Wxp, Whp, bb, zxbuf, h0, h1, flags, go, out, Tc);
}

// Round 4
// 1085.088 us; speedup vs baseline: 3.1700x; 1.7080x over previous
//
#include <hip/hip_runtime.h>

// LSTM: B=512, T=128, D=512, H=512, gates [i|j|f|o], FORGET_BIAS=1.0
// Persistent kernel, 256 blocks (16 row-tiles x 16 gate-col-tiles), 1 block/CU.
// Per chunk: (a) GEMM phase zx = b + x@Wx (block-private, no sync),
// (b) recurrence: Wh in LDS, h exchanged via sc1 atomics with cooperative
// LDS staging, per-row-group producer flags (no global barrier, no fences).

#define Bsz 512
#define Tt  128
#define Dd  512
#define Hh  512
#define NB  256

typedef _Float16 half8 __attribute__((ext_vector_type(8)));
typedef _Float16 half4 __attribute__((ext_vector_type(4)));
typedef float    f32x4 __attribute__((ext_vector_type(4)));
typedef unsigned long long u64;

__device__ __forceinline__ float sigm(float v) { return 1.0f / (1.0f + __expf(-v)); }
__device__ __forceinline__ float tanhfast(float v) {
    float e = __expf(-2.0f * fabsf(v));
    float r = (1.0f - e) / (1.0f + e);
    return (v < 0.0f) ? -r : r;
}

// Pack W -> fragment-major f16 for both Wx (rows 0..511) and Wh (rows 512..1023).
// Slice layout per (f = ct*4+wv): [hn(2)][kc(16)][lane(64)][8], element j =
// W[koff + kc*32 + (lane>>4)*8 + j][wv*512 + ct*32 + hn*16 + (lane&15)].
__global__ __launch_bounds__(256) void pack_kernel(const float* __restrict__ W,
                                                   _Float16* __restrict__ Wxp,
                                                   _Float16* __restrict__ Whp) {
    __shared__ _Float16 Tl[512 * 32];   // [k][n] tile, 32 KB
    const int bid = blockIdx.x, tid = threadIdx.x;
    const int which = bid >> 6;          // 0: Wx, 1: Wh
    const int f = bid & 63, ct = f >> 2, wv = f & 3;
    const int koff = which * 512;
    const int ncol0 = wv * Hh + ct * 32;

#pragma unroll
    for (int p = 0; p < 16; ++p) {
        int row = p * 32 + (tid >> 3);
        int c4  = (tid & 7) * 4;
        float4 v = *reinterpret_cast<const float4*>(W + (size_t)(koff + row) * 2048 + ncol0 + c4);
        Tl[row * 32 + c4 + 0] = (_Float16)v.x;
        Tl[row * 32 + c4 + 1] = (_Float16)v.y;
        Tl[row * 32 + c4 + 2] = (_Float16)v.z;
        Tl[row * 32 + c4 + 3] = (_Float16)v.w;
    }
    __syncthreads();

    _Float16* dst = (which ? Whp : Wxp) + (size_t)f * 16384;
#pragma unroll
    for (int i = 0; i < 8; ++i) {
        int gi  = tid * 8 + i;               // 0..2047
        int hn  = gi >> 10;
        int kc  = (gi >> 6) & 15;
        int ln  = gi & 63;
        int l15 = ln & 15, l16 = ln >> 4;
        half8 v;
#pragma unroll
        for (int j = 0; j < 8; ++j)
            v[j] = Tl[(kc * 32 + l16 * 8 + j) * 32 + hn * 16 + l15];
        *reinterpret_cast<half8*>(dst + (size_t)gi * 8) = v;
    }
}

__global__ __launch_bounds__(256) void lstm_all(
    const float* __restrict__ x, const _Float16* __restrict__ Wxp,
    const _Float16* __restrict__ Whp, const float* __restrict__ bias,
    _Float16* __restrict__ zxbuf, _Float16* __restrict__ h0,
    _Float16* __restrict__ h1, unsigned int* __restrict__ flags,
    float* __restrict__ out, int Tc) {

    // [0,16384): GEMM x-staging | recurrence h quarters (2x8KB) | Z exchange
    // [16384, 16384+131072): W fragments (Wx in GEMM phase, Wh in recurrence)
    __shared__ __align__(16) char smem[16384 + 131072];
    half8* Wlds = reinterpret_cast<half8*>(smem + 16384);

    const int tid = threadIdx.x, lane = tid & 63, wv = tid >> 6;
    const int l15 = lane & 15, l16 = lane >> 4;
    const int bid = blockIdx.x;
    const int rt = (bid & 7) * 2 + ((bid >> 3) & 1);  // 0..15 (bijection of bid&15)
    const int ct = bid >> 4;                          // 0..15

    const float bias0 = bias[wv * Hh + ct * 32 + l15]      + (wv == 2 ? 1.0f : 0.0f);
    const float bias1 = bias[wv * Hh + ct * 32 + 16 + l15] + (wv == 2 ? 1.0f : 0.0f);

    const int srow = tid >> 3, sl8 = tid & 7;         // GEMM staging / h staging
    const int erow = tid >> 3, ecol = (tid & 7) * 4;  // pointwise
    float creg[4] = {0.f, 0.f, 0.f, 0.f};

    const int nChunks = Tt / Tc;

    for (int cc = 0; cc < nChunks; ++cc) {
        // ================= GEMM phase: zx = bias + x@Wx (block-local) =================
        {   // load Wx fragments -> LDS
            const half8* s8 = reinterpret_cast<const half8*>(Wxp + (size_t)(ct * 4) * 16384);
#pragma unroll
            for (int i = 0; i < 32; ++i) Wlds[tid + i * 256] = s8[tid + i * 256];
        }
        __syncthreads();

        for (int t16 = 0; t16 < Tc; ++t16) {
            const int tg = cc * Tc + t16;
            f32x4 acc00 = {bias0, bias0, bias0, bias0};
            f32x4 acc10 = acc00;
            f32x4 acc01 = {bias1, bias1, bias1, bias1};
            f32x4 acc11 = acc01;

#pragma unroll
            for (int kh = 0; kh < 2; ++kh) {
                // stage 32 rows x 256 cols of x as f16 (swizzled)
                const float* xr = x + ((size_t)(rt * 32 + srow) * Tt + tg) * Dd + kh * 256;
#pragma unroll
                for (int i = 0; i < 4; ++i) {
                    int k8 = sl8 + i * 8;            // 0..31 (16B groups)
                    float4 p0 = *reinterpret_cast<const float4*>(xr + k8 * 8);
                    float4 p1 = *reinterpret_cast<const float4*>(xr + k8 * 8 + 4);
                    half8 v;
                    v[0] = (_Float16)p0.x; v[1] = (_Float16)p0.y;
                    v[2] = (_Float16)p0.z; v[3] = (_Float16)p0.w;
                    v[4] = (_Float16)p1.x; v[5] = (_Float16)p1.y;
                    v[6] = (_Float16)p1.z; v[7] = (_Float16)p1.w;
                    *reinterpret_cast<half8*>(smem + srow * 512 + ((k8 * 16) ^ ((srow & 7) << 4))) = v;
                }
                __syncthreads();
#pragma unroll
                for (int k2 = 0; k2 < 8; ++k2) {
                    int kc = kh * 8 + k2;
                    int kg = k2 * 4 + l16;
                    half8 a0 = *reinterpret_cast<const half8*>(
                        smem + l15 * 512 + ((kg * 16) ^ ((l15 & 7) << 4)));
                    half8 a1 = *reinterpret_cast<const half8*>(
                        smem + (16 + l15) * 512 + ((kg * 16) ^ ((l15 & 7) << 4)));
                    half8 b0 = Wlds[((wv * 2 + 0) * 16 + kc) * 64 + lane];
                    half8 b1 = Wlds[((wv * 2 + 1) * 16 + kc) * 64 + lane];
                    acc00 = __builtin_amdgcn_mfma_f32_16x16x32_f16(a0, b0, acc00, 0, 0, 0);
                    acc10 = __builtin_amdgcn_mfma_f32_16x16x32_f16(a1, b0, acc10, 0, 0, 0);
                    acc01 = __builtin_amdgcn_mfma_f32_16x16x32_f16(a0, b1, acc01, 0, 0, 0);
                    acc11 = __builtin_amdgcn_mfma_f32_16x16x32_f16(a1, b1, acc11, 0, 0, 0);
                }
                __syncthreads();
            }
            // store zx fragments (block-private, f16, normal cached stores)
            _Float16* zp = zxbuf + (((size_t)bid * Tc + t16) * 4 + wv) * 1024 + lane * 16;
            half8 z0, z1;
#pragma unroll
            for (int r = 0; r < 4; ++r) {
                z0[r] = (_Float16)acc00[r]; z0[4 + r] = (_Float16)acc10[r];
                z1[r] = (_Float16)acc01[r]; z1[4 + r] = (_Float16)acc11[r];
            }
            *reinterpret_cast<half8*>(zp)     = z0;
            *reinterpret_cast<half8*>(zp + 8) = z1;
        }

        {   // load Wh fragments -> LDS
            const half8* s8 = reinterpret_cast<const half8*>(Whp + (size_t)(ct * 4) * 16384);
#pragma unroll
            for (int i = 0; i < 32; ++i) Wlds[tid + i * 256] = s8[tid + i * 256];
        }
        __syncthreads();

        // ================= recurrence phase =================
#pragma unroll 1
        for (int t16 = 0; t16 < Tc; ++t16) {
            const int tg = cc * Tc + t16;
            const _Float16* hin = (tg & 1) ? h1 : h0;
            _Float16* hout      = (tg & 1) ? h0 : h1;

            // acc init from zx (includes bias; block-private normal loads)
            const _Float16* zp = zxbuf + (((size_t)bid * Tc + t16) * 4 + wv) * 1024 + lane * 16;
            half8 z0 = *reinterpret_cast<const half8*>(zp);
            half8 z1 = *reinterpret_cast<const half8*>(zp + 8);
            f32x4 acc00, acc10, acc01, acc11;
#pragma unroll
            for (int r = 0; r < 4; ++r) {
                acc00[r] = (float)z0[r]; acc10[r] = (float)z0[4 + r];
                acc01[r] = (float)z1[r]; acc11[r] = (float)z1[4 + r];
            }

            // wait for the 16 producers of this row group (direct flag poll)
            if (tid < 16) {
                const unsigned int* fp = flags + ((unsigned)(bid & 15) + 16u * (unsigned)tid) * 16u;
                while (__hip_atomic_load(fp, __ATOMIC_RELAXED, __HIP_MEMORY_SCOPE_AGENT)
                       < (unsigned)tg)
                    __builtin_amdgcn_s_sleep(1);
            }
            __syncthreads();

            // cooperative h gather: all 32 KB issued as one pipelined sc1 burst
            const u64* hq = reinterpret_cast<const u64*>(
                                hin + (size_t)(rt * 32 + srow) * Hh) + sl8 * 4;
            u64 hr[16];
#pragma unroll
            for (int q = 0; q < 4; ++q)
#pragma unroll
                for (int j = 0; j < 4; ++j)
                    hr[q * 4 + j] = __hip_atomic_load(hq + q * 32 + j, __ATOMIC_RELAXED,
                                                      __HIP_MEMORY_SCOPE_AGENT);

            const int wb = srow * 256;                 // LDS row base (256 B rows)
#pragma unroll
            for (int half = 0; half < 2; ++half) {
                // stage quarters {2*half, 2*half+1} into bufs A(0)/B(8192)
#pragma unroll
                for (int j = 0; j < 4; ++j) {
                    int sw = wb + ((sl8 * 32 + j * 8) ^ ((srow & 7) << 4));
                    *reinterpret_cast<u64*>(smem + sw)        = hr[(2 * half) * 4 + j];
                    *reinterpret_cast<u64*>(smem + 8192 + sw) = hr[(2 * half + 1) * 4 + j];
                }
                __syncthreads();
#pragma unroll
                for (int qb = 0; qb < 2; ++qb) {
#pragma unroll
                    for (int kq = 0; kq < 4; ++kq) {
                        int kc = half * 8 + qb * 4 + kq;
                        int boff = kq * 64 + l16 * 16;
                        half8 a0 = *reinterpret_cast<const half8*>(
                            smem + qb * 8192 + l15 * 256 + (boff ^ ((l15 & 7) << 4)));
                        half8 a1 = *reinterpret_cast<const half8*>(
                            smem + qb * 8192 + (16 + l15) * 256 + (boff ^ (((16 + l15) & 7) << 4)));
                        half8 b0 = Wlds[((wv * 2 + 0) * 16 + kc) * 64 + lane];
                        half8 b1 = Wlds[((wv * 2 + 1) * 16 + kc) * 64 + lane];
                        acc00 = __builtin_amdgcn_mfma_f32_16x16x32_f16(a0, b0, acc00, 0, 0, 0);
                        acc10 = __builtin_amdgcn_mfma_f32_16x16x32_f16(a1, b0, acc10, 0, 0, 0);
                        acc01 = __builtin_amdgcn_mfma_f32_16x16x32_f16(a0, b1, acc01, 0, 0, 0);
                        acc11 = __builtin_amdgcn_mfma_f32_16x16x32_f16(a1, b1, acc11, 0, 0, 0);
                    }
                }
                __syncthreads();   // all reads of smem[0:16K) done before re-staging / Z
            }

            // Z scatter: swizzled [4][32][32] f32, byte = (g*32+row)*128 + ((col*4)^((row&7)<<4))
#pragma unroll
            for (int reg = 0; reg < 4; ++reg) {
                int zr = l16 * 4 + reg;       // C/D: col=lane&15, row=(lane>>4)*4+reg
                *reinterpret_cast<float*>(smem + (wv * 32 + zr) * 128
                    + ((l15 * 4) ^ ((zr & 7) << 4)))              = acc00[reg];
                *reinterpret_cast<float*>(smem + (wv * 32 + 16 + zr) * 128
                    + ((l15 * 4) ^ ((zr & 7) << 4)))              = acc10[reg];
                *reinterpret_cast<float*>(smem + (wv * 32 + zr) * 128
                    + (((16 + l15) * 4) ^ ((zr & 7) << 4)))       = acc01[reg];
                *reinterpret_cast<float*>(smem + (wv * 32 + 16 + zr) * 128
                    + (((16 + l15) * 4) ^ ((zr & 7) << 4)))       = acc11[reg];
            }
            __syncthreads();

            // pointwise c/h update (c register-resident)
            float hv[4];
            {
                int swz = (ecol * 4) ^ ((erow & 7) << 4);
                f32x4 vi = *reinterpret_cast<const f32x4*>(smem + (0 * 32 + erow) * 128 + swz);
                f32x4 vj = *reinterpret_cast<const f32x4*>(smem + (1 * 32 + erow) * 128 + swz);
                f32x4 vf = *reinterpret_cast<const f32x4*>(smem + (2 * 32 + erow) * 128 + swz);
                f32x4 vo = *reinterpret_cast<const f32x4*>(smem + (3 * 32 + erow) * 128 + swz);
#pragma unroll
                for (int q = 0; q < 4; ++q) {
                    float cn = creg[q] * sigm(vf[q]) + sigm(vi[q]) * tanhfast(vj[q]);
                    creg[q] = cn;
                    hv[q] = tanhfast(cn) * sigm(vo[q]);
                }
            }
            {
                size_t off = (size_t)(rt * 32 + erow) * Hh + ct * 32 + ecol;
                half4 hh;
                hh[0] = (_Float16)hv[0]; hh[1] = (_Float16)hv[1];
                hh[2] = (_Float16)hv[2]; hh[3] = (_Float16)hv[3];
                u64 hraw = __builtin_bit_cast(u64, hh);
                __hip_atomic_store(reinterpret_cast<u64*>(hout) + (off >> 2), hraw,
                                   __ATOMIC_RELAXED, __HIP_MEMORY_SCOPE_AGENT);
                if (tg == Tt - 1) {
                    f32x4 fo; fo[0] = hv[0]; fo[1] = hv[1]; fo[2] = hv[2]; fo[3] = hv[3];
                    *reinterpret_cast<f32x4*>(out + off) = fo;
                }
            }

            // post readiness flag (monotone); syncthreads drains all sc1 h-stores first
            if (tg < Tt - 1) {
                __syncthreads();
                if (tid == 0)
                    __hip_atomic_store(&flags[bid * 16], (unsigned)(tg + 1),
                                       __ATOMIC_RELAXED, __HIP_MEMORY_SCOPE_AGENT);
            }
        }
    }
}

extern "C" void kernel_launch(void* const* d_in, const int* in_sizes, int n_in,
                              void* d_out, int out_size, void* d_ws, size_t ws_size,
                              hipStream_t stream) {
    const float* x  = (const float*)d_in[0];   // [512,128,512] f32
    const float* W  = (const float*)d_in[1];   // [1024,2048] f32
    const float* bb = (const float*)d_in[2];   // [2048] f32
    float* out = (float*)d_out;                // [512,512] f32

    char* ws = (char*)d_ws;
    _Float16* Wxp = (_Float16*)ws;                                   // 2 MB
    _Float16* Whp = (_Float16*)(ws + (2u << 20));                    // 2 MB
    _Float16* h0  = (_Float16*)(ws + (4u << 20));                    // 512 KB
    _Float16* h1  = (_Float16*)(ws + (4u << 20) + (512u << 10));     // 512 KB
    unsigned int* flags = (unsigned int*)(ws + (5u << 20));          // 256 x 64B
    _Float16* zxbuf = (_Float16*)(ws + (6u << 20));                  // Tc * 2 MB

    int Tc = 16;
    while (Tc > 1 && (size_t)(6u << 20) + (size_t)NB * Tc * 4096 * 2 > ws_size) Tc >>= 1;

    hipMemsetAsync(h0, 0, (size_t)Bsz * Hh * sizeof(_Float16), stream);
    hipMemsetAsync((void*)flags, 0, 16384, stream);
    pack_kernel<<<128, 256, 0, stream>>>(W, Wxp, Whp);
    lstm_all<<<256, 256, 0, stream>>>(x, Wxp, Whp, bb, zxbuf, h0, h1, flags, out, Tc);
}

// Round 5
// 690.164 us; speedup vs baseline: 4.9839x; 1.5722x over previous
//
#include <hip/hip_runtime.h>

// LSTM: B=512, T=128, D=512, H=512, gates [i|j|f|o], FORGET_BIAS=1.0
// Persistent kernel, 256 blocks (16 row-tiles x 16 gate-col-tiles), 1 block/CU,
// 1 wave/SIMD. Wx/Wh fragments in VGPRs (128+128 per thread). Per step t the
// block also computes zx(t+4) = b + x_{t+4} @ Wx into an 8-slot LDS ring,
// split around the flag-poll and h-gather to hide sync/gather latency.
// h exchanged via device-scope (sc1) relaxed atomics; per-row-group producer
// flags (fence-free, monotone).

#define Tt  128
#define Dd  512
#define Hh  512

typedef _Float16 half8 __attribute__((ext_vector_type(8)));
typedef _Float16 half4 __attribute__((ext_vector_type(4)));
typedef float    f32x4 __attribute__((ext_vector_type(4)));
typedef unsigned long long u64;

#define MF(a,b,c) __builtin_amdgcn_mfma_f32_16x16x32_f16(a,b,c,0,0,0)

#define HZ_OFF   0        // 16 KB: h-stage quarters (2x8K) / Z exchange overlay
#define RING_OFF 16384    // 64 KB: zx ring, 8 slots x 8 KB
#define X_OFF    81920    // 32 KB: x stage (32 rows x 1024 B swizzled)
#define SMEM_SZ  114688

__device__ __forceinline__ float sigm(float v) { return 1.0f / (1.0f + __expf(-v)); }
__device__ __forceinline__ float tanhfast(float v) {
    float e = __expf(-2.0f * fabsf(v));
    float r = (1.0f - e) / (1.0f + e);
    return (v < 0.0f) ? -r : r;
}
__device__ __forceinline__ half8 mk16(u64 a, u64 b) {
    half4 x = __builtin_bit_cast(half4, a), y = __builtin_bit_cast(half4, b);
    half8 r;
    r[0] = x[0]; r[1] = x[1]; r[2] = x[2]; r[3] = x[3];
    r[4] = y[0]; r[5] = y[1]; r[6] = y[2]; r[7] = y[3];
    return r;
}

// Pack W [1024,2048] f32 -> fragment-major f16 slices (verified rounds 2-4).
// Slice f = ct*4+wv: [hn(2)][kc(16)][lane(64)][8]; element j =
// W[koff + kc*32 + (lane>>4)*8 + j][wv*512 + ct*32 + hn*16 + (lane&15)].
__global__ __launch_bounds__(256) void pack_kernel(const float* __restrict__ W,
                                                   _Float16* __restrict__ Wxp,
                                                   _Float16* __restrict__ Whp) {
    __shared__ _Float16 Tl[512 * 32];
    const int bid = blockIdx.x, tid = threadIdx.x;
    const int which = bid >> 6;
    const int f = bid & 63, ct = f >> 2, wv = f & 3;
    const int koff = which * 512;
    const int ncol0 = wv * Hh + ct * 32;

#pragma unroll
    for (int p = 0; p < 16; ++p) {
        int row = p * 32 + (tid >> 3);
        int c4  = (tid & 7) * 4;
        float4 v = *reinterpret_cast<const float4*>(W + (size_t)(koff + row) * 2048 + ncol0 + c4);
        Tl[row * 32 + c4 + 0] = (_Float16)v.x;
        Tl[row * 32 + c4 + 1] = (_Float16)v.y;
        Tl[row * 32 + c4 + 2] = (_Float16)v.z;
        Tl[row * 32 + c4 + 3] = (_Float16)v.w;
    }
    __syncthreads();

    _Float16* dst = (which ? Whp : Wxp) + (size_t)f * 16384;
#pragma unroll
    for (int i = 0; i < 8; ++i) {
        int gi  = tid * 8 + i;
        int hn  = gi >> 10;
        int kc  = (gi >> 6) & 15;
        int ln  = gi & 63;
        int l15 = ln & 15, l16 = ln >> 4;
        half8 v;
#pragma unroll
        for (int j = 0; j < 8; ++j)
            v[j] = Tl[(kc * 32 + l16 * 8 + j) * 32 + hn * 16 + l15];
        *reinterpret_cast<half8*>(dst + (size_t)gi * 8) = v;
    }
}

__global__ __launch_bounds__(256, 1) void lstm_all(
    const float* __restrict__ x, const _Float16* __restrict__ Wxp,
    const _Float16* __restrict__ Whp, const float* __restrict__ bias,
    _Float16* __restrict__ h0, _Float16* __restrict__ h1,
    unsigned int* __restrict__ flags, float* __restrict__ out) {

    __shared__ __align__(16) char smem[SMEM_SZ];

    const int tid = threadIdx.x, lane = tid & 63, wv = tid >> 6;
    const int l15 = lane & 15, l16 = lane >> 4;
    const int bid = blockIdx.x;
    const int rt = (bid & 7) * 2 + ((bid >> 3) & 1);  // 0..15 (bijection of bid&15)
    const int ct = bid >> 4;                          // 0..15

    // ---- W fragments -> registers (per wave: its gate's slices) ----
    half8 wx[32], wh[32];
    {
        const half8* wxs = reinterpret_cast<const half8*>(Wxp) + (size_t)(ct * 4 + wv) * 2048;
        const half8* whs = reinterpret_cast<const half8*>(Whp) + (size_t)(ct * 4 + wv) * 2048;
#pragma unroll
        for (int kc = 0; kc < 16; ++kc) {
#pragma unroll
            for (int hn = 0; hn < 2; ++hn) {
                wx[kc * 2 + hn] = wxs[hn * 1024 + kc * 64 + lane];
                wh[kc * 2 + hn] = whs[hn * 1024 + kc * 64 + lane];
            }
        }
    }

    const float bias0 = bias[wv * Hh + ct * 32 + l15]      + (wv == 2 ? 1.0f : 0.0f);
    const float bias1 = bias[wv * Hh + ct * 32 + 16 + l15] + (wv == 2 ? 1.0f : 0.0f);

    const int srow = tid >> 3, sl8 = tid & 7;
    const int erow = tid >> 3, ecol = (tid & 7) * 4;
    float creg[4] = {0.f, 0.f, 0.f, 0.f};

    f32x4 accG00, accG01, accG10, accG11;   // zx GEMM accumulators

    // stage x_g (f32 -> f16, swizzled) into X_OFF
    auto stage_x = [&](int g) {
        const float* xr = x + ((size_t)(rt * 32 + srow) * Tt + g) * Dd;
        float4 xf[16];
#pragma unroll
        for (int i = 0; i < 8; ++i) {
            int k8 = sl8 + i * 8;
            xf[2 * i]     = *reinterpret_cast<const float4*>(xr + k8 * 8);
            xf[2 * i + 1] = *reinterpret_cast<const float4*>(xr + k8 * 8 + 4);
        }
#pragma unroll
        for (int i = 0; i < 8; ++i) {
            int k8 = sl8 + i * 8;
            half8 v;
            v[0] = (_Float16)xf[2*i].x;   v[1] = (_Float16)xf[2*i].y;
            v[2] = (_Float16)xf[2*i].z;   v[3] = (_Float16)xf[2*i].w;
            v[4] = (_Float16)xf[2*i+1].x; v[5] = (_Float16)xf[2*i+1].y;
            v[6] = (_Float16)xf[2*i+1].z; v[7] = (_Float16)xf[2*i+1].w;
            *reinterpret_cast<half8*>(smem + X_OFF + srow * 1024
                                      + ((k8 * 16) ^ ((srow & 7) << 4))) = v;
        }
    };

    auto gemm_half = [&](int h) {   // h=0: kc 0..7, h=1: kc 8..15
#pragma unroll
        for (int k2 = 0; k2 < 8; ++k2) {
            int kc = h * 8 + k2;
            int kg = kc * 4 + l16;
            half8 a0 = *reinterpret_cast<const half8*>(
                smem + X_OFF + l15 * 1024 + ((kg * 16) ^ ((l15 & 7) << 4)));
            half8 a1 = *reinterpret_cast<const half8*>(
                smem + X_OFF + (16 + l15) * 1024 + ((kg * 16) ^ ((l15 & 7) << 4)));
            accG00 = MF(a0, wx[kc * 2 + 0], accG00);
            accG10 = MF(a1, wx[kc * 2 + 0], accG10);
            accG01 = MF(a0, wx[kc * 2 + 1], accG01);
            accG11 = MF(a1, wx[kc * 2 + 1], accG11);
        }
    };

    auto ring_write = [&](int g) {
        half8 z0, z1;
#pragma unroll
        for (int r = 0; r < 4; ++r) {
            z0[r] = (_Float16)accG00[r]; z0[4 + r] = (_Float16)accG10[r];
            z1[r] = (_Float16)accG01[r]; z1[4 + r] = (_Float16)accG11[r];
        }
        char* rp = smem + RING_OFF + (g & 7) * 8192 + wv * 2048 + lane * 16;
        *reinterpret_cast<half8*>(rp)        = z0;
        *reinterpret_cast<half8*>(rp + 1024) = z1;
    };

    // ---------- prologue: zx for steps 0..3 ----------
#pragma unroll 1
    for (int p = 0; p < 4; ++p) {
        stage_x(p);
        __syncthreads();
        accG00 = f32x4{bias0, bias0, bias0, bias0}; accG10 = accG00;
        accG01 = f32x4{bias1, bias1, bias1, bias1}; accG11 = accG01;
        gemm_half(0); gemm_half(1);
        ring_write(p);
        __syncthreads();
    }

    // ---------- main loop ----------
#pragma unroll 1
    for (int t = 0; t < Tt; ++t) {
        const int g = t + 4;
        const bool do_g = (g < Tt);
        const _Float16* hin = (t & 1) ? h1 : h0;
        _Float16* hout      = (t & 1) ? h0 : h1;

        if (do_g) stage_x(g);
        __syncthreads();                     // xbuf ready; hZ arena free

        if (do_g) {
            accG00 = f32x4{bias0, bias0, bias0, bias0}; accG10 = accG00;
            accG01 = f32x4{bias1, bias1, bias1, bias1}; accG11 = accG01;
            gemm_half(0);                    // absorbs flag-visibility latency
        }

        // wait for the 16 producers of this row group
        if (tid < 16) {
            const unsigned int* fp = flags + ((unsigned)(bid & 15) + 16u * (unsigned)tid) * 16u;
            while (__hip_atomic_load(fp, __ATOMIC_RELAXED, __HIP_MEMORY_SCOPE_AGENT)
                   < (unsigned)t)
                __builtin_amdgcn_s_sleep(1);
        }
        __syncthreads();

        // cooperative h gather (sc1 burst, 32 KB)
        const u64* hq = reinterpret_cast<const u64*>(
                            hin + (size_t)(rt * 32 + srow) * Hh) + sl8 * 4;
        u64 hr[16];
#pragma unroll
        for (int q = 0; q < 4; ++q)
#pragma unroll
            for (int j = 0; j < 4; ++j)
                hr[q * 4 + j] = __hip_atomic_load(hq + q * 32 + j, __ATOMIC_RELAXED,
                                                  __HIP_MEMORY_SCOPE_AGENT);

        if (do_g) {                          // absorbs gather latency
            gemm_half(1);
            ring_write(g);
        }

        // acc init from zx ring slot t
        f32x4 acc00, acc10, acc01, acc11;
        {
            const char* rp = smem + RING_OFF + (t & 7) * 8192 + wv * 2048 + lane * 16;
            half8 z0 = *reinterpret_cast<const half8*>(rp);
            half8 z1 = *reinterpret_cast<const half8*>(rp + 1024);
#pragma unroll
            for (int r = 0; r < 4; ++r) {
                acc00[r] = (float)z0[r]; acc10[r] = (float)z0[4 + r];
                acc01[r] = (float)z1[r]; acc11[r] = (float)z1[4 + r];
            }
        }

        // recurrence: 2 halves of K, quarters staged into hZ arena
#pragma unroll
        for (int half = 0; half < 2; ++half) {
            // stage quarters {2*half, 2*half+1} as b128 pairs
#pragma unroll
            for (int c = 0; c < 2; ++c) {
                int off = srow * 256 + ((sl8 * 32 + c * 16) ^ ((srow & 7) << 4));
                *reinterpret_cast<half8*>(smem + off) =
                    mk16(hr[(2 * half) * 4 + 2 * c], hr[(2 * half) * 4 + 2 * c + 1]);
                *reinterpret_cast<half8*>(smem + 8192 + off) =
                    mk16(hr[(2 * half + 1) * 4 + 2 * c], hr[(2 * half + 1) * 4 + 2 * c + 1]);
            }
            __syncthreads();
#pragma unroll
            for (int qb = 0; qb < 2; ++qb) {
#pragma unroll
                for (int kq = 0; kq < 4; ++kq) {
                    int kc = half * 8 + qb * 4 + kq;
                    int boff = kq * 64 + l16 * 16;
                    half8 a0 = *reinterpret_cast<const half8*>(
                        smem + qb * 8192 + l15 * 256 + (boff ^ ((l15 & 7) << 4)));
                    half8 a1 = *reinterpret_cast<const half8*>(
                        smem + qb * 8192 + (16 + l15) * 256 + (boff ^ ((l15 & 7) << 4)));
                    acc00 = MF(a0, wh[kc * 2 + 0], acc00);
                    acc10 = MF(a1, wh[kc * 2 + 0], acc10);
                    acc01 = MF(a0, wh[kc * 2 + 1], acc01);
                    acc11 = MF(a1, wh[kc * 2 + 1], acc11);
                }
            }
            __syncthreads();
        }

        // Z scatter (swizzled [4][32][32] f32 in hZ arena)
#pragma unroll
        for (int reg = 0; reg < 4; ++reg) {
            int zr = l16 * 4 + reg;       // C/D: col=lane&15, row=(lane>>4)*4+reg
            *reinterpret_cast<float*>(smem + (wv * 32 + zr) * 128
                + ((l15 * 4) ^ ((zr & 7) << 4)))              = acc00[reg];
            *reinterpret_cast<float*>(smem + (wv * 32 + 16 + zr) * 128
                + ((l15 * 4) ^ ((zr & 7) << 4)))              = acc10[reg];
            *reinterpret_cast<float*>(smem + (wv * 32 + zr) * 128
                + (((16 + l15) * 4) ^ ((zr & 7) << 4)))       = acc01[reg];
            *reinterpret_cast<float*>(smem + (wv * 32 + 16 + zr) * 128
                + (((16 + l15) * 4) ^ ((zr & 7) << 4)))       = acc11[reg];
        }
        __syncthreads();

        // pointwise c/h update
        float hv[4];
        {
            int swz = (ecol * 4) ^ ((erow & 7) << 4);
            f32x4 vi = *reinterpret_cast<const f32x4*>(smem + (0 * 32 + erow) * 128 + swz);
            f32x4 vj = *reinterpret_cast<const f32x4*>(smem + (1 * 32 + erow) * 128 + swz);
            f32x4 vf = *reinterpret_cast<const f32x4*>(smem + (2 * 32 + erow) * 128 + swz);
            f32x4 vo = *reinterpret_cast<const f32x4*>(smem + (3 * 32 + erow) * 128 + swz);
#pragma unroll
            for (int q = 0; q < 4; ++q) {
                float cn = creg[q] * sigm(vf[q]) + sigm(vi[q]) * tanhfast(vj[q]);
                creg[q] = cn;
                hv[q] = tanhfast(cn) * sigm(vo[q]);
            }
        }
        {
            size_t off = (size_t)(rt * 32 + erow) * Hh + ct * 32 + ecol;
            half4 hh;
            hh[0] = (_Float16)hv[0]; hh[1] = (_Float16)hv[1];
            hh[2] = (_Float16)hv[2]; hh[3] = (_Float16)hv[3];
            u64 hraw = __builtin_bit_cast(u64, hh);
            __hip_atomic_store(reinterpret_cast<u64*>(hout) + (off >> 2), hraw,
                               __ATOMIC_RELAXED, __HIP_MEMORY_SCOPE_AGENT);
            if (t == Tt - 1) {
                f32x4 fo; fo[0] = hv[0]; fo[1] = hv[1]; fo[2] = hv[2]; fo[3] = hv[3];
                *reinterpret_cast<f32x4*>(out + off) = fo;
            }
        }

        // drain h stores (syncthreads emits vmcnt(0)), then post flag
        __syncthreads();
        if (t < Tt - 1 && tid == 0)
            __hip_atomic_store(&flags[bid * 16], (unsigned)(t + 1),
                               __ATOMIC_RELAXED, __HIP_MEMORY_SCOPE_AGENT);
    }
}

extern "C" void kernel_launch(void* const* d_in, const int* in_sizes, int n_in,
                              void* d_out, int out_size, void* d_ws, size_t ws_size,
                              hipStream_t stream) {
    const float* x  = (const float*)d_in[0];   // [512,128,512] f32
    const float* W  = (const float*)d_in[1];   // [1024,2048] f32
    const float* bb = (const float*)d_in[2];   // [2048] f32
    float* out = (float*)d_out;                // [512,512] f32

    char* ws = (char*)d_ws;
    _Float16* Wxp = (_Float16*)ws;                                   // 2 MB
    _Float16* Whp = (_Float16*)(ws + (2u << 20));                    // 2 MB
    _Float16* h0  = (_Float16*)(ws + (4u << 20));                    // 512 KB
    _Float16* h1  = (_Float16*)(ws + (4u << 20) + (512u << 10));     // 512 KB
    unsigned int* flags = (unsigned int*)(ws + (5u << 20));          // 256 x 64B

    hipMemsetAsync(h0, 0, (size_t)512 * Hh * sizeof(_Float16), stream);
    hipMemsetAsync((void*)flags, 0, 16384, stream);
    pack_kernel<<<128, 256, 0, stream>>>(W, Wxp, Whp);
    lstm_all<<<256, 256, 0, stream>>>(x, Wxp, Whp, bb, h0, h1, flags, out);
}